// Round 3
// baseline (319.021 us; speedup 1.0000x reference)
//
#include <hip/hip_runtime.h>

// PPNM layer: out = m + b_s[:,None] * m*m, m = x @ W
//   x: [B, 16] fp32, W: [16, 224] fp32, b_s: [B] fp32, out: [B, 224] fp32
//
// Memory-bound: 235 MB write + ~18 MB read => ~40 us floor at 6.3 TB/s.
//
// R4 == R3 resubmitted verbatim: R3's bench died with an infrastructure
// error ("MI355X container failed twice") before producing counters, so
// the spill theory below is still untested. Source audited for hang/OOB
// paths: loop is monotone with explicit break; all prefetch indices
// clamped to [0, tiles-1]; no LDS; no capture-hostile host calls.
//
// R3 changes vs R2 (R2 kernel-proper ~147 us = 1.7 TB/s effective):
//  - THEORY: R1/R2 spilled VGPRs. __launch_bounds__(448,4) caps VGPRs at
//    128; live state was Wf(64) + 2 pipeline stages(34) + xs/acc/addr
//    (~40) ~= 140 -> ~12 dwords/lane/iter of scratch spill+refill. Scratch
//    is HBM-backed: 229K wave-iters x ~3 KB ~= 720 MB hidden traffic --
//    exactly the gap between 252 MB logical and the ~970 MB implied by
//    147 us at the fill kernel's 6.6 TB/s. Depth-2 prefetch (R2) was
//    worth only 9 us because latency was never the binding constraint.
//  - FIX: halve per-thread W footprint. Each thread covers 2 bands
//    (float2 Wf = 32 VGPRs), GROUPS=112 x PROWS=4 = same 448 threads.
//    Total live state ~80 VGPRs -> no spill possible under the 128 cap,
//    and occupancy headroom rises. Wave still stores 512 contiguous
//    bytes (dwordx2 x 64 lanes) -> identical L2-line coverage.
//  - Prefetch indices clamped with min() instead of branched -> single
//    basic block, precise counted waitcnt, no divergent CFG.

#define LBANDS 224
#define EMEMB  16
#define GROUPS 112                 // LBANDS / 2: thread covers bands [2g, 2g+2)
#define PROWS  4                   // pixel rows per block tile
#define NTHREADS (GROUPS * PROWS)  // 448 = 7 full waves

__global__ __launch_bounds__(NTHREADS, 4) void ppnm_kernel(
    const float* __restrict__ x,    // [B, 16]
    const float* __restrict__ w,    // [16, 224]
    const float* __restrict__ bs,   // [B]
    float* __restrict__ out,        // [B, 224]
    int B)
{
    const int t  = threadIdx.x;
    const int g  = t % GROUPS;   // band pair: bands [2g, 2g+1]
    const int pr = t / GROUPS;   // pixel row within tile: 0..3

    // W fragment: Wf[k] = w[k][2g..2g+1]. 32 VGPRs (was 64 -> spill cause).
    float2 Wf[EMEMB];
    #pragma unroll
    for (int k = 0; k < EMEMB; ++k) {
        Wf[k] = *reinterpret_cast<const float2*>(w + k * LBANDS + 2 * g);
    }

    const int tiles  = B / PROWS;   // 65536 for B=262144
    const int stride = gridDim.x;

    int tile = blockIdx.x;
    if (tile >= tiles) return;

    // ---- software pipeline, depth 2 ----
    float4 a0, b0, c0, d0; float s0;
    float4 a1, b1, c1, d1; float s1;

    {
        const int p = tile * PROWS + pr;
        const float4* xr = reinterpret_cast<const float4*>(x + p * EMEMB);
        a0 = xr[0]; b0 = xr[1]; c0 = xr[2]; d0 = xr[3];
        s0 = bs[p];
    }
    {
        const int tn = min(tile + stride, tiles - 1);   // clamped, branch-free
        const int p  = tn * PROWS + pr;
        const float4* xr = reinterpret_cast<const float4*>(x + p * EMEMB);
        a1 = xr[0]; b1 = xr[1]; c1 = xr[2]; d1 = xr[3];
        s1 = bs[p];
    }

    // m = x_row . W[:, 2g:2g+2] (32 FMAs, 2 chains); out = m + b*m*m.
#define PPNM_BODY(AA, BB, CC, DD, SS, TT) do {                                \
        const float xs_[EMEMB] = { AA.x, AA.y, AA.z, AA.w,                    \
                                   BB.x, BB.y, BB.z, BB.w,                    \
                                   CC.x, CC.y, CC.z, CC.w,                    \
                                   DD.x, DD.y, DD.z, DD.w };                  \
        float2 acc = make_float2(0.f, 0.f);                                   \
        _Pragma("unroll")                                                     \
        for (int k = 0; k < EMEMB; ++k) {                                     \
            acc.x = fmaf(xs_[k], Wf[k].x, acc.x);                             \
            acc.y = fmaf(xs_[k], Wf[k].y, acc.y);                             \
        }                                                                     \
        float2 r;                                                             \
        r.x = fmaf((SS) * acc.x, acc.x, acc.x);                               \
        r.y = fmaf((SS) * acc.y, acc.y, acc.y);                               \
        *reinterpret_cast<float2*>(out + ((TT) * PROWS + pr) * LBANDS + 2 * g) = r; \
    } while (0)

#define PPNM_PREFETCH(AA, BB, CC, DD, SS, TT) do {                            \
        const int p_ = (TT) * PROWS + pr;                                     \
        const float4* xr_ = reinterpret_cast<const float4*>(x + p_ * EMEMB);  \
        AA = xr_[0]; BB = xr_[1]; CC = xr_[2]; DD = xr_[3];                   \
        SS = bs[p_];                                                          \
    } while (0)

    for (;;) {
        // consume stage0 (current tile), refill it for tile + 2*stride (clamped)
        PPNM_BODY(a0, b0, c0, d0, s0, tile);
        {
            const int tn = min(tile + 2 * stride, tiles - 1);
            PPNM_PREFETCH(a0, b0, c0, d0, s0, tn);
        }
        tile += stride;
        if (tile >= tiles) break;

        // consume stage1, refill for tile + 2*stride (clamped)
        PPNM_BODY(a1, b1, c1, d1, s1, tile);
        {
            const int tn = min(tile + 2 * stride, tiles - 1);
            PPNM_PREFETCH(a1, b1, c1, d1, s1, tn);
        }
        tile += stride;
        if (tile >= tiles) break;
    }

#undef PPNM_BODY
#undef PPNM_PREFETCH
}

extern "C" void kernel_launch(void* const* d_in, const int* in_sizes, int n_in,
                              void* d_out, int out_size, void* d_ws, size_t ws_size,
                              hipStream_t stream) {
    const float* x  = (const float*)d_in[0];   // [B, 16]
    const float* w  = (const float*)d_in[1];   // [16, 224]
    const float* bs = (const float*)d_in[2];   // [B]
    float* out = (float*)d_out;

    const int B = in_sizes[2];                 // 262144

    // 4096 blocks: 16 tiles each amortize the per-thread W-fragment load
    // (Wf is only 32 VGPRs now); tiles = B/4 = 65536.
    const int grid = 4096;
    ppnm_kernel<<<grid, NTHREADS, 0, stream>>>(x, w, bs, out, B);
}

// Round 4
// 288.502 us; speedup vs baseline: 1.1058x; 1.1058x over previous
//
#include <hip/hip_runtime.h>

// PPNM layer: out = m + b_s[:,None] * m*m, m = x @ W
//   x: [B, 16] fp32, W: [16, 224] fp32, b_s: [B] fp32, out: [B, 224] fp32
//
// Memory-bound: 235 MB write + ~18 MB read => ~40 us floor at 6.3 TB/s.
//
// R5 vs R2 (best so far, 287.2 us; R3's footprint cut REGRESSED to 319):
//  - THEORY: vmcnt is a single IN-ORDER counter for loads and stores.
//    R2's per-stage order was {store -> prefetch loads}; the next
//    iteration's wait for those loads therefore drained the OLDER store
//    too. Every wave retired its store to the L2 ack point every
//    iteration -> stores never fire-and-forget (~1-2 in flight/wave),
//    store-retire latency on the critical path, ~1.9 TB/s effective vs
//    the fill kernel's 6.6 TB/s (which never waits on its stores).
//    Explains R2's tiny +9us from prefetch depth (loads were hidden,
//    stores weren't) and R3's +32us (2x iterations = 2x store drains).
//  - FIX (single structural change): per-stage order is now
//    {compute -> prefetch loads -> store}. The awaited loads are older
//    than all stores, so the compiler's s_waitcnt becomes a counted
//    vmcnt(>=6) that leaves stores in flight indefinitely.
//  - Hygiene (predicted codegen-neutral): xs_[16] array replaced with
//    direct float4-component FMAs (same accumulation order -> identical
//    numerics), removing any scratch-demotion risk.
//  - Geometry/grid/launch_bounds identical to R2 for a clean A/B:
//    448 threads = 7 full waves, wave stores 1024 contiguous bytes,
//    __launch_bounds__(448,4), grid 2048, depth-2 pipeline.

#define LBANDS 224
#define EMEMB  16
#define GROUPS 56                  // LBANDS / 4
#define PROWS  8                   // pixel rows per block tile
#define NTHREADS (GROUPS * PROWS)  // 448 = 7 full waves

__global__ __launch_bounds__(NTHREADS, 4) void ppnm_kernel(
    const float* __restrict__ x,    // [B, 16]
    const float* __restrict__ w,    // [16, 224]
    const float* __restrict__ bs,   // [B]
    float* __restrict__ out,        // [B, 224]
    int B)
{
    const int t  = threadIdx.x;
    const int g  = t % GROUPS;   // band group: bands [4g, 4g+4)
    const int pr = t / GROUPS;   // pixel row within tile: 0..7

    // W fragment: Wf[k] = w[k][4g..4g+3]. 64 VGPRs, loaded once.
    float4 Wf[EMEMB];
    #pragma unroll
    for (int k = 0; k < EMEMB; ++k) {
        Wf[k] = *reinterpret_cast<const float4*>(w + k * LBANDS + 4 * g);
    }

    const int tiles  = B / PROWS;   // 32768 for B=262144
    const int stride = gridDim.x;

    int tile = blockIdx.x;
    if (tile >= tiles) return;

    // ---- software pipeline, depth 2 ----
    float4 a0, b0, c0, d0; float s0;
    float4 a1, b1, c1, d1; float s1;

    {
        const int p = tile * PROWS + pr;
        const float4* xr = reinterpret_cast<const float4*>(x + p * EMEMB);
        a0 = xr[0]; b0 = xr[1]; c0 = xr[2]; d0 = xr[3];
        s0 = bs[p];
    }
    {
        const int tn = min(tile + stride, tiles - 1);   // clamped, branch-free
        const int p  = tn * PROWS + pr;
        const float4* xr = reinterpret_cast<const float4*>(x + p * EMEMB);
        a1 = xr[0]; b1 = xr[1]; c1 = xr[2]; d1 = xr[3];
        s1 = bs[p];
    }

    // 4 k-steps of the dot product from one float4 of x.
    // Accumulation order per component is identical to R2's k=0..15 loop.
#define PPNM_FMA4(SCAL, K)                                                    \
        acc.x = fmaf((SCAL), Wf[K].x, acc.x);                                 \
        acc.y = fmaf((SCAL), Wf[K].y, acc.y);                                 \
        acc.z = fmaf((SCAL), Wf[K].z, acc.z);                                 \
        acc.w = fmaf((SCAL), Wf[K].w, acc.w);

    // m = x_row . W[:, 4g:4g+4]; r = m + b*m*m  (no store here).
#define PPNM_COMPUTE(RR, AA, BB, CC, DD, SS) do {                             \
        float4 acc = make_float4(0.f, 0.f, 0.f, 0.f);                         \
        PPNM_FMA4(AA.x,  0) PPNM_FMA4(AA.y,  1)                               \
        PPNM_FMA4(AA.z,  2) PPNM_FMA4(AA.w,  3)                               \
        PPNM_FMA4(BB.x,  4) PPNM_FMA4(BB.y,  5)                               \
        PPNM_FMA4(BB.z,  6) PPNM_FMA4(BB.w,  7)                               \
        PPNM_FMA4(CC.x,  8) PPNM_FMA4(CC.y,  9)                               \
        PPNM_FMA4(CC.z, 10) PPNM_FMA4(CC.w, 11)                               \
        PPNM_FMA4(DD.x, 12) PPNM_FMA4(DD.y, 13)                               \
        PPNM_FMA4(DD.z, 14) PPNM_FMA4(DD.w, 15)                               \
        RR.x = fmaf((SS) * acc.x, acc.x, acc.x);                              \
        RR.y = fmaf((SS) * acc.y, acc.y, acc.y);                              \
        RR.z = fmaf((SS) * acc.z, acc.z, acc.z);                              \
        RR.w = fmaf((SS) * acc.w, acc.w, acc.w);                              \
    } while (0)

#define PPNM_PREFETCH(AA, BB, CC, DD, SS, TT) do {                            \
        const int p_ = (TT) * PROWS + pr;                                     \
        const float4* xr_ = reinterpret_cast<const float4*>(x + p_ * EMEMB);  \
        AA = xr_[0]; BB = xr_[1]; CC = xr_[2]; DD = xr_[3];                   \
        SS = bs[p_];                                                          \
    } while (0)

#define PPNM_STORE(RR, TT)                                                    \
        *reinterpret_cast<float4*>(out + ((TT) * PROWS + pr) * LBANDS + 4 * g) = RR;

    for (;;) {
        // stage0: compute -> prefetch (loads BEFORE store) -> store
        {
            float4 r0;
            PPNM_COMPUTE(r0, a0, b0, c0, d0, s0);
            const int tn = min(tile + 2 * stride, tiles - 1);
            PPNM_PREFETCH(a0, b0, c0, d0, s0, tn);
            PPNM_STORE(r0, tile);
        }
        tile += stride;
        if (tile >= tiles) break;

        // stage1: compute -> prefetch -> store
        {
            float4 r1;
            PPNM_COMPUTE(r1, a1, b1, c1, d1, s1);
            const int tn = min(tile + 2 * stride, tiles - 1);
            PPNM_PREFETCH(a1, b1, c1, d1, s1, tn);
            PPNM_STORE(r1, tile);
        }
        tile += stride;
        if (tile >= tiles) break;
    }

#undef PPNM_FMA4
#undef PPNM_COMPUTE
#undef PPNM_PREFETCH
#undef PPNM_STORE
}

extern "C" void kernel_launch(void* const* d_in, const int* in_sizes, int n_in,
                              void* d_out, int out_size, void* d_ws, size_t ws_size,
                              hipStream_t stream) {
    const float* x  = (const float*)d_in[0];   // [B, 16]
    const float* w  = (const float*)d_in[1];   // [16, 224]
    const float* bs = (const float*)d_in[2];   // [B]
    float* out = (float*)d_out;

    const int B = in_sizes[2];                 // 262144

    // 2048 blocks: 16 tiles each amortize the per-thread W-fragment load;
    // ~2 resident blocks/CU (14 waves) under the 128-VGPR cap.
    const int grid = 2048;
    ppnm_kernel<<<grid, NTHREADS, 0, stream>>>(x, w, bs, out, B);
}

// Round 5
// 257.231 us; speedup vs baseline: 1.2402x; 1.1216x over previous
//
#include <hip/hip_runtime.h>

// PPNM layer: out = m + b_s[:,None] * m*m, m = x @ W
//   x: [B, 16] fp32, W: [16, 224] fp32, b_s: [B] fp32, out: [B, 224] fp32
//
// Memory-bound: 235 MB write + ~18 MB read => ~40 us floor at 6.3 TB/s.
//
// R6 vs R2/R5 (both ~287-288; kernel-proper ~107 us):
//  - EVIDENCE: R3's doubled iteration count cost +32 us for +229K
//    wave-iters => ~340 unoverlapped cycles per wave-iteration; issue
//    work is only ~170 cyc/iter. Stalls scale with ITERATION COUNT, not
//    bytes (prefetch depth: null) nor registers (footprint cut: worse)
//    nor source memop order (restrict makes it a scheduler choice: null).
//  - FIX: amortize. 32-pixel bodies staged in LDS:
//      * cooperative stage: 2 KB x-slab + 128 B bs per body, ONE
//        coalesced global read (threads 0-159) instead of every thread
//        loading its pixel row (56-way redundant).
//      * each thread computes 4 pixels x 4 bands per body from LDS
//        broadcast reads (same-address ds_read = conflict-free).
//      * wave-iterations: 229K -> 57K (4x fewer wait events).
//      * T14 split: issue next body's global loads at body top, ds_write
//        them after compute, ONE barrier per body -> ~1000 cycles of FMA
//        cover the load latency.
//  - Registers: Wf 64 + x-frag 16 + acc/r 8 + addr ~15 ~= 105 < 128 cap
//    (pipeline stage regs eliminated -- x lives in LDS now).
//  - LDS: 2 x (2KB + 128B) = 4.4 KB, not occupancy-limiting.
//  - FMA order per output identical to R2/R5 -> absmax unchanged.

#define LBANDS 224
#define EMEMB  16
#define GROUPS 56                   // band groups: thread owns bands [4g, 4g+4)
#define PPHASE 8                    // pixel phases per body
#define NTHREADS (GROUPS * PPHASE)  // 448 = 7 full waves
#define PPB    32                   // pixels per body (thread: 4 pixels)
#define XCHUNKS (PPB * 4)           // 128 float4 chunks of x per body

__global__ __launch_bounds__(NTHREADS, 4) void ppnm_kernel(
    const float* __restrict__ x,    // [B, 16]
    const float* __restrict__ w,    // [16, 224]
    const float* __restrict__ bs,   // [B]
    float* __restrict__ out,        // [B, 224]
    int B)
{
    const int t  = threadIdx.x;
    const int g  = t % GROUPS;   // band group: bands [4g, 4g+4)
    const int pw = t / GROUPS;   // pixel phase: handles pixels pw+8j, j=0..3

    // W fragment: Wf[k] = w[k][4g..4g+3]. 64 VGPRs, loaded once per block.
    float4 Wf[EMEMB];
    #pragma unroll
    for (int k = 0; k < EMEMB; ++k) {
        Wf[k] = *reinterpret_cast<const float4*>(w + k * LBANDS + 4 * g);
    }

    // Double-buffered x slab + bs slice.
    __shared__ float4 xsh[2][XCHUNKS];   // [buf][pixel*4 + quarter]
    __shared__ float  bsh[2][PPB];

    const int bodies  = B / PPB;         // 8192 for B=262144
    const int bstride = gridDim.x;       // 2048 -> 4 bodies per block

    int body = blockIdx.x;
    if (body >= bodies) return;

    const float4* xv = reinterpret_cast<const float4*>(x);

    // --- prologue: stage first body into buf 0 ---
    if (t < XCHUNKS) {
        xsh[0][t] = xv[body * XCHUNKS + t];
    } else if (t < XCHUNKS + PPB) {
        bsh[0][t - XCHUNKS] = bs[body * PPB + (t - XCHUNKS)];
    }
    __syncthreads();

#define PPNM_FMA4(SCAL, K)                                                    \
        acc.x = fmaf((SCAL), Wf[K].x, acc.x);                                 \
        acc.y = fmaf((SCAL), Wf[K].y, acc.y);                                 \
        acc.z = fmaf((SCAL), Wf[K].z, acc.z);                                 \
        acc.w = fmaf((SCAL), Wf[K].w, acc.w);

    int cur = 0;
    for (;;) {
        const int nbody     = body + bstride;
        const bool have_next = (nbody < bodies);

        // T14 issue-early: next body's global loads go in flight now;
        // the 4-pixel FMA block below (~1000 cycles) hides their latency.
        float4 xstage = make_float4(0.f, 0.f, 0.f, 0.f);
        float  bstage = 0.f;
        if (have_next) {
            if (t < XCHUNKS) {
                xstage = xv[nbody * XCHUNKS + t];
            } else if (t < XCHUNKS + PPB) {
                bstage = bs[nbody * PPB + (t - XCHUNKS)];
            }
        }

        // --- compute 4 pixels (pw + 8j) from LDS[cur] ---
        #pragma unroll
        for (int j = 0; j < PPB / PPHASE; ++j) {
            const int px = pw + PPHASE * j;          // pixel within body
            const float4 xa = xsh[cur][px * 4 + 0];  // broadcast reads
            const float4 xb = xsh[cur][px * 4 + 1];
            const float4 xc = xsh[cur][px * 4 + 2];
            const float4 xd = xsh[cur][px * 4 + 3];
            const float  sb = bsh[cur][px];

            float4 acc = make_float4(0.f, 0.f, 0.f, 0.f);
            PPNM_FMA4(xa.x,  0) PPNM_FMA4(xa.y,  1)
            PPNM_FMA4(xa.z,  2) PPNM_FMA4(xa.w,  3)
            PPNM_FMA4(xb.x,  4) PPNM_FMA4(xb.y,  5)
            PPNM_FMA4(xb.z,  6) PPNM_FMA4(xb.w,  7)
            PPNM_FMA4(xc.x,  8) PPNM_FMA4(xc.y,  9)
            PPNM_FMA4(xc.z, 10) PPNM_FMA4(xc.w, 11)
            PPNM_FMA4(xd.x, 12) PPNM_FMA4(xd.y, 13)
            PPNM_FMA4(xd.z, 14) PPNM_FMA4(xd.w, 15)

            float4 r;
            r.x = fmaf(sb * acc.x, acc.x, acc.x);
            r.y = fmaf(sb * acc.y, acc.y, acc.y);
            r.z = fmaf(sb * acc.z, acc.z, acc.z);
            r.w = fmaf(sb * acc.w, acc.w, acc.w);

            // wave's 64 lanes cover 1024 contiguous bytes; body's 32 rows
            // form one 28 KB contiguous output slab -> pure streaming.
            *reinterpret_cast<float4*>(out + (body * PPB + px) * LBANDS + 4 * g) = r;
        }

        if (!have_next) break;

        // write-late: staged regs -> LDS[next]; one barrier per body.
        if (t < XCHUNKS) {
            xsh[cur ^ 1][t] = xstage;
        } else if (t < XCHUNKS + PPB) {
            bsh[cur ^ 1][t - XCHUNKS] = bstage;
        }
        __syncthreads();

        body = nbody;
        cur ^= 1;
    }

#undef PPNM_FMA4
}

extern "C" void kernel_launch(void* const* d_in, const int* in_sizes, int n_in,
                              void* d_out, int out_size, void* d_ws, size_t ws_size,
                              hipStream_t stream) {
    const float* x  = (const float*)d_in[0];   // [B, 16]
    const float* w  = (const float*)d_in[1];   // [16, 224]
    const float* bs = (const float*)d_in[2];   // [B]
    float* out = (float*)d_out;

    const int B = in_sizes[2];                 // 262144

    // 2048 blocks, bodies = B/32 = 8192 -> 4 bodies per block (grid-stride);
    // ~2 resident blocks/CU (14 waves) under the 128-VGPR cap.
    const int grid = 2048;
    ppnm_kernel<<<grid, NTHREADS, 0, stream>>>(x, w, bs, out, B);
}

// Round 6
// 245.313 us; speedup vs baseline: 1.3005x; 1.0486x over previous
//
#include <hip/hip_runtime.h>

// PPNM layer: out = m + b_s[:,None] * m*m, m = x @ W
//   x: [B, 16] fp32, W: [16, 224] fp32, b_s: [B] fp32, out: [B, 224] fp32
//
// Memory-bound: 235 MB write + ~18 MB read => ~40 us floor at 6.3 TB/s.
//
// R7 vs R6 (257.2 us; kernel-proper ~76 us vs ~40 us write roofline):
//  - EVIDENCE: stall cost scales with per-wave wait EVENTS, confirmed
//    both directions (R3: +229K iters = +32 us; R6: -172K iters = -31 us).
//    R6's residual: one __syncthreads per 32-pixel body. hipcc emits a
//    full s_waitcnt vmcnt(0) lgkmcnt(0) before s_barrier (documented
//    structural drain), so every body drained its 4 stores + staged
//    loads to the ack point -- 57K drain events at store-retire latency.
//    The 6.6 TB/s fill kernel NEVER waits on a store.
//  - FIX: one body per block. PPB=128, grid = B/128 = 2048 blocks:
//      * stage 8 KB x-slab + 512 B bs cooperatively, ONE barrier,
//      * then 16 pixels/thread of pure FMA + 16 fire-and-forget stores,
//        zero further waits until wave retire (the fill kernel's regime).
//    Barrier/drain events: 57K -> 2K (one per block).
//  - No grid-stride loop, no double buffer -> VGPR ~90 (Wf 64 + temps).
//  - Per-wave store mapping byte-identical to R6 (56+8 float4 chunks of
//    two adjacent rows; body slab is 112 KB contiguous). FMA order per
//    output identical -> absmax unchanged.

#define LBANDS 224
#define EMEMB  16
#define GROUPS 56                   // band groups: thread owns bands [4g, 4g+4)
#define PPHASE 8                    // pixel phases
#define NTHREADS (GROUPS * PPHASE)  // 448 = 7 full waves
#define PPB    128                  // pixels per block (thread: 16 pixels)
#define XCHUNKS (PPB * 4)           // 512 float4 chunks of x per block

__global__ __launch_bounds__(NTHREADS, 4) void ppnm_kernel(
    const float* __restrict__ x,    // [B, 16]
    const float* __restrict__ w,    // [16, 224]
    const float* __restrict__ bs,   // [B]
    float* __restrict__ out,        // [B, 224]
    int B)
{
    const int t  = threadIdx.x;
    const int g  = t % GROUPS;   // band group: bands [4g, 4g+4)
    const int pw = t / GROUPS;   // pixel phase: handles pixels pw+8j, j=0..15

    const int body = blockIdx.x;
    if (body * PPB >= B) return;

    // Single-buffered x slab + bs slice (one body per block -> no dbuf).
    __shared__ float4 xsh[XCHUNKS];   // [pixel*4 + quarter]
    __shared__ float  bsh[PPB];

    // --- cooperative stage: issue all staging loads first ---
    const float4* xv = reinterpret_cast<const float4*>(x);
    const float4  v0 = xv[body * XCHUNKS + t];                         // chunks 0..447
    float4 v1 = make_float4(0.f, 0.f, 0.f, 0.f);
    if (t < XCHUNKS - NTHREADS)                                        // chunks 448..511
        v1 = xv[body * XCHUNKS + NTHREADS + t];
    float bv = 0.f;
    if (t < PPB)                                                       // bs 0..127
        bv = bs[body * PPB + t];

    // W fragment: Wf[k] = w[k][4g..4g+3]. 64 VGPRs; w is L2-hot (14 KB).
    // Issued after the staging loads so the stage is oldest in vmcnt.
    float4 Wf[EMEMB];
    #pragma unroll
    for (int k = 0; k < EMEMB; ++k) {
        Wf[k] = *reinterpret_cast<const float4*>(w + k * LBANDS + 4 * g);
    }

    xsh[t] = v0;
    if (t < XCHUNKS - NTHREADS) xsh[NTHREADS + t] = v1;
    if (t < PPB)                bsh[t] = bv;
    __syncthreads();   // the ONLY barrier: one drain per block, not per body

#define PPNM_FMA4(SCAL, K)                                                    \
        acc.x = fmaf((SCAL), Wf[K].x, acc.x);                                 \
        acc.y = fmaf((SCAL), Wf[K].y, acc.y);                                 \
        acc.z = fmaf((SCAL), Wf[K].z, acc.z);                                 \
        acc.w = fmaf((SCAL), Wf[K].w, acc.w);

    // --- 16 pixels per thread, pure FMA + fire-and-forget stores ---
    #pragma unroll
    for (int j = 0; j < PPB / PPHASE; ++j) {
        const int px = pw + PPHASE * j;          // pixel within body: 0..127
        const float4 xa = xsh[px * 4 + 0];       // broadcast reads (same addr
        const float4 xb = xsh[px * 4 + 1];       //  across most lanes of wave)
        const float4 xc = xsh[px * 4 + 2];
        const float4 xd = xsh[px * 4 + 3];
        const float  sb = bsh[px];

        float4 acc = make_float4(0.f, 0.f, 0.f, 0.f);
        PPNM_FMA4(xa.x,  0) PPNM_FMA4(xa.y,  1)
        PPNM_FMA4(xa.z,  2) PPNM_FMA4(xa.w,  3)
        PPNM_FMA4(xb.x,  4) PPNM_FMA4(xb.y,  5)
        PPNM_FMA4(xb.z,  6) PPNM_FMA4(xb.w,  7)
        PPNM_FMA4(xc.x,  8) PPNM_FMA4(xc.y,  9)
        PPNM_FMA4(xc.z, 10) PPNM_FMA4(xc.w, 11)
        PPNM_FMA4(xd.x, 12) PPNM_FMA4(xd.y, 13)
        PPNM_FMA4(xd.z, 14) PPNM_FMA4(xd.w, 15)

        float4 r;
        r.x = fmaf(sb * acc.x, acc.x, acc.x);
        r.y = fmaf(sb * acc.y, acc.y, acc.y);
        r.z = fmaf(sb * acc.z, acc.z, acc.z);
        r.w = fmaf(sb * acc.w, acc.w, acc.w);

        // body slab = 112 KB contiguous; wave covers 1024B across two
        // adjacent rows -> pure streaming, never awaited.
        *reinterpret_cast<float4*>(out + (body * PPB + px) * LBANDS + 4 * g) = r;
    }

#undef PPNM_FMA4
}

extern "C" void kernel_launch(void* const* d_in, const int* in_sizes, int n_in,
                              void* d_out, int out_size, void* d_ws, size_t ws_size,
                              hipStream_t stream) {
    const float* x  = (const float*)d_in[0];   // [B, 16]
    const float* w  = (const float*)d_in[1];   // [16, 224]
    const float* bs = (const float*)d_in[2];   // [B]
    float* out = (float*)d_out;

    const int B = in_sizes[2];                 // 262144

    // One 128-pixel body per block: grid = B/128 = 2048.
    const int grid = (B + PPB - 1) / PPB;
    ppnm_kernel<<<grid, NTHREADS, 0, stream>>>(x, w, bs, out, B);
}